// Round 4
// baseline (381.057 us; speedup 1.0000x reference)
//
#include <hip/hip_runtime.h>

#define L 2048
#define E 128
#define NB 8

typedef float f32x4 __attribute__((ext_vector_type(4)));
typedef short short8 __attribute__((ext_vector_type(8)));

static __device__ inline float bf2f(ushort u) {
  union { float f; unsigned int i; } v; v.i = ((unsigned int)u) << 16; return v.f;
}
static __device__ inline ushort f2bf(float f) {
  union { float f; unsigned int i; } v; v.f = f;
  unsigned int x = v.i;
  return (ushort)((x + 0x7fffu + ((x >> 16) & 1u)) >> 16);  // RTNE
}

// ---------------------------------------------------------------------------
// dtype detect: scan even 16-bit halves of Uq. fp32 data -> those are mantissa
// fragments with ~uniform exponent bits; bf16 N(0,1) data never has exp>=140.
// flag=1 => inputs are fp32.
// ---------------------------------------------------------------------------
__global__ __launch_bounds__(256) void k_detect(const ushort* __restrict__ raw,
                                                int* __restrict__ flag) {
  int t = threadIdx.x;
  int bad = 0;
  for (int k = t; k < 8192; k += 256) {
    ushort u = raw[2 * k];
    int e = (u >> 7) & 0xFF;
    if (e >= 140) bad = 1;
  }
  __shared__ int any;
  if (t == 0) any = 0;
  __syncthreads();
  if (bad) atomicOr(&any, 1);
  __syncthreads();
  if (t == 0) *flag = any;
}

// ---------------------------------------------------------------------------
// convert: dst(bf16)[i] = flag ? f2bf(src_f32[i]) : src_bf16[i]
// ---------------------------------------------------------------------------
__global__ __launch_bounds__(256) void k_convert(const void* __restrict__ src,
                                                 ushort* __restrict__ dst,
                                                 long n, const int* __restrict__ flag) {
  long i = (long)blockIdx.x * 256 + threadIdx.x;
  if (i >= n) return;
  if (*flag) dst[i] = f2bf(((const float*)src)[i]);
  else       dst[i] = ((const ushort*)src)[i];
}

// ---------------------------------------------------------------------------
// prep: s_id, s_q, Uidw = Uid*w_mul, out[:,:,0:128] = Uid  (all-bf16 inputs)
// ---------------------------------------------------------------------------
__global__ __launch_bounds__(128) void k_prep(const ushort* __restrict__ Uid,
                                              const ushort* __restrict__ Uq,
                                              const ushort* __restrict__ Wcw,
                                              ushort* __restrict__ Uidw,
                                              float* __restrict__ s_id,
                                              float* __restrict__ s_q,
                                              void* __restrict__ out,
                                              const int* __restrict__ flag) {
  int r = blockIdx.x;          // 0..B*L-1
  int e = threadIdx.x;         // 0..127
  ushort uidu = Uid[(long)r * E + e];
  ushort uqu  = Uq[(long)r * E + e];
  float uidf = bf2f(uidu), uqf = bf2f(uqu);
  float wid = bf2f(Wcw[e]), wq = bf2f(Wcw[E + e]), wmul = bf2f(Wcw[2 * E + e]);
  float sid = uidf * wid, sq = uqf * wq;
  #pragma unroll
  for (int off = 32; off >= 1; off >>= 1) {
    sid += __shfl_down(sid, off, 64);
    sq  += __shfl_down(sq,  off, 64);
  }
  __shared__ float red[4];
  int wv = threadIdx.x >> 6;
  if ((threadIdx.x & 63) == 0) { red[wv * 2] = sid; red[wv * 2 + 1] = sq; }
  __syncthreads();
  if (threadIdx.x == 0) { s_id[r] = red[0] + red[2]; s_q[r] = red[1] + red[3]; }
  Uidw[(long)r * E + e] = f2bf(uidf * wmul);
  if (*flag) ((float*)out)[(long)r * 512 + e] = uidf;
  else       ((ushort*)out)[(long)r * 512 + e] = uidu;
}

// ---------------------------------------------------------------------------
// GEMM tile core: C[m,n] = sum_k A[m,k]*B[n,k], 64x64 tile, 4 waves,
// mfma_f32_16x16x32_bf16. LDS: 64 rows x 40 ushorts, k-contiguous.
// MODE 0 (NT): row-major [rows x ld], k contiguous; ptr at tile row 0.
// MODE 1 (TN): row-major [k x ld], m/n contiguous; ptr at tile col 0.
// ---------------------------------------------------------------------------
template <int MODE>
__device__ inline void stage_tile(const ushort* __restrict__ src, long ldS,
                                  int k0, ushort* lds, int t) {
  if (MODE == 0) {
    int row = t >> 2, kc = (t & 3) << 3;
    *(uint4*)&lds[row * 40 + kc] = *(const uint4*)&src[(long)row * ldS + k0 + kc];
  } else {
    int kr = t >> 3, cs = (t & 7) << 3;
    uint4 v = *(const uint4*)&src[(long)(k0 + kr) * ldS + cs];
    ushort* pv = (ushort*)&v;
    #pragma unroll
    for (int u = 0; u < 8; u++) lds[(cs + u) * 40 + kr] = pv[u];
  }
}

template <int AMODE, int BMODE>
__device__ inline void gemm_tile(const ushort* __restrict__ Ab,
                                 const ushort* __restrict__ Bb,
                                 long ldA, long ldB, int K,
                                 f32x4 acc[4],
                                 ushort* ldsA, ushort* ldsB) {
  const int t    = threadIdx.x;
  const int lane = t & 63;
  const int wv   = t >> 6;
  const int mrow = lane & 15;
  const int quad = lane >> 4;
  for (int k0 = 0; k0 < K; k0 += 32) {
    __syncthreads();
    stage_tile<AMODE>(Ab, ldA, k0, ldsA, t);
    stage_tile<BMODE>(Bb, ldB, k0, ldsB, t);
    __syncthreads();
    short8 av = *(const short8*)&ldsA[(wv * 16 + mrow) * 40 + quad * 8];
    #pragma unroll
    for (int nb = 0; nb < 4; nb++) {
      short8 bv = *(const short8*)&ldsB[(nb * 16 + mrow) * 40 + quad * 8];
      acc[nb] = __builtin_amdgcn_mfma_f32_16x16x32_bf16(av, bv, acc[nb], 0, 0, 0);
    }
  }
}

// ---------------------------------------------------------------------------
// scores: St[bz,j,i] = (dot(Uq[j],Uidw[i]) + s_q[j] + s_id[i] + bias)*mask[i,j]
// ---------------------------------------------------------------------------
__global__ __launch_bounds__(256) void k_scores(const ushort* __restrict__ Uq,
                                                const ushort* __restrict__ Uidw,
                                                const float* __restrict__ s_id,
                                                const float* __restrict__ s_q,
                                                const ushort* __restrict__ Wcb,
                                                const ushort* __restrict__ mask,
                                                ushort* __restrict__ St, int b0) {
  __shared__ ushort ldsA[64 * 40];
  __shared__ ushort ldsB[64 * 40];
  int bz = blockIdx.z, b = b0 + bz;
  int m0 = blockIdx.x * 64;   // j
  int n0 = blockIdx.y * 64;   // i
  const ushort* Ab = Uq   + (long)b * L * E + (long)m0 * E;
  const ushort* Bb = Uidw + (long)b * L * E + (long)n0 * E;
  f32x4 acc[4] = {};
  gemm_tile<0, 0>(Ab, Bb, E, E, E, acc, ldsA, ldsB);
  float bias = bf2f(Wcb[0]);
  int lane = threadIdx.x & 63, wv = threadIdx.x >> 6;
  int col = lane & 15, quad = lane >> 4;
  #pragma unroll
  for (int nb = 0; nb < 4; nb++) {
    int ig = n0 + nb * 16 + col;
    float sidv = s_id[b * L + ig];
    #pragma unroll
    for (int rg = 0; rg < 4; rg++) {
      int jg = m0 + wv * 16 + quad * 4 + rg;
      float v = (acc[nb][rg] + s_q[b * L + jg] + sidv + bias)
                * bf2f(mask[(long)ig * L + jg]);
      St[(long)bz * L * L + (long)jg * L + ig] = f2bf(v);
    }
  }
}

// ---------------------------------------------------------------------------
// in-place row softmax (length 2048), bf16; NaN inputs squashed to -1e30
// ---------------------------------------------------------------------------
__global__ __launch_bounds__(256) void k_softmax(ushort* __restrict__ S) {
  long r = blockIdx.x;
  ushort* row = S + r * L;
  int t = threadIdx.x;
  uint4 raw = *(const uint4*)&row[t * 8];
  ushort* pr = (ushort*)&raw;
  float v[8];
  float mx = -1e30f;
  #pragma unroll
  for (int q = 0; q < 8; q++) {
    v[q] = bf2f(pr[q]);
    if (!(v[q] == v[q])) v[q] = -1e30f;   // NaN guard (diagnostic)
    mx = fmaxf(mx, v[q]);
  }
  #pragma unroll
  for (int off = 32; off >= 1; off >>= 1) mx = fmaxf(mx, __shfl_xor(mx, off, 64));
  __shared__ float red[8];
  int wv = t >> 6;
  if ((t & 63) == 0) red[wv] = mx;
  __syncthreads();
  mx = fmaxf(fmaxf(red[0], red[1]), fmaxf(red[2], red[3]));
  float s = 0.f;
  #pragma unroll
  for (int q = 0; q < 8; q++) { v[q] = __expf(v[q] - mx); s += v[q]; }
  #pragma unroll
  for (int off = 32; off >= 1; off >>= 1) s += __shfl_xor(s, off, 64);
  if ((t & 63) == 0) red[4 + wv] = s;
  __syncthreads();
  float inv = 1.0f / (red[4] + red[5] + red[6] + red[7]);
  ushort o[8];
  #pragma unroll
  for (int q = 0; q < 8; q++) o[q] = f2bf(v[q] * inv);
  *(uint4*)&row[t * 8] = *(uint4*)o;
}

// ---------------------------------------------------------------------------
// T[b,j,e] = sum_i Pt[bz,j,i] * Uid[b,i,e]
// ---------------------------------------------------------------------------
__global__ __launch_bounds__(256) void k_gemm_T(const ushort* __restrict__ Pt,
                                                const ushort* __restrict__ Uid,
                                                ushort* __restrict__ T, int b0) {
  __shared__ ushort ldsA[64 * 40];
  __shared__ ushort ldsB[64 * 40];
  int bz = blockIdx.z, b = b0 + bz;
  int m0 = blockIdx.x * 64;   // j
  int n0 = blockIdx.y * 64;   // e
  const ushort* Ab = Pt  + (long)bz * L * L + (long)m0 * L;
  const ushort* Bb = Uid + (long)b * L * E + n0;
  f32x4 acc[4] = {};
  gemm_tile<0, 1>(Ab, Bb, L, E, L, acc, ldsA, ldsB);
  int lane = threadIdx.x & 63, wv = threadIdx.x >> 6;
  int col = lane & 15, quad = lane >> 4;
  #pragma unroll
  for (int nb = 0; nb < 4; nb++) {
    int eg = n0 + nb * 16 + col;
    #pragma unroll
    for (int rg = 0; rg < 4; rg++) {
      int jg = m0 + wv * 16 + quad * 4 + rg;
      T[(long)b * L * E + (long)jg * E + eg] = f2bf(acc[nb][rg]);
    }
  }
}

// ---------------------------------------------------------------------------
// final: C[b,i,c] = sum_j Pt[bz,j,i] * X[b,j,c], X = [Uq | T]
// writes out cols 128..511 as bf16 or fp32 per flag
// ---------------------------------------------------------------------------
__global__ __launch_bounds__(256) void k_gemm_A(const ushort* __restrict__ Pt,
                                                const ushort* __restrict__ Uq,
                                                const ushort* __restrict__ T,
                                                const ushort* __restrict__ Uid,
                                                void* __restrict__ out, int b0,
                                                const int* __restrict__ flag) {
  __shared__ ushort ldsA[64 * 40];
  __shared__ ushort ldsB[64 * 40];
  int bz = blockIdx.z, b = b0 + bz;
  int m0 = blockIdx.x * 64;   // i
  int n0 = blockIdx.y * 64;   // c in [0,256)
  const ushort* Ab = Pt + (long)bz * L * L + m0;
  const ushort* Bb = (n0 < 128) ? (Uq + (long)b * L * E + n0)
                                : (T  + (long)b * L * E + (n0 - 128));
  f32x4 acc[4] = {};
  gemm_tile<1, 1>(Ab, Bb, L, E, L, acc, ldsA, ldsB);
  int lane = threadIdx.x & 63, wv = threadIdx.x >> 6;
  int col = lane & 15, quad = lane >> 4;
  int fp32out = *flag;
  #pragma unroll
  for (int nb = 0; nb < 4; nb++) {
    int c = n0 + nb * 16 + col;
    #pragma unroll
    for (int rg = 0; rg < 4; rg++) {
      int ig = m0 + wv * 16 + quad * 4 + rg;
      float uidf = bf2f(Uid[(long)b * L * E + (long)ig * E + (c & 127)]);
      float a = acc[nb][rg];
      long ob = ((long)b * L + ig) * 512;
      if (fp32out) {
        float* of = (float*)out;
        if (c < 128) { of[ob + 128 + c] = a; of[ob + 256 + c] = uidf * a; }
        else         { of[ob + 256 + c] = uidf * a; }
      } else {
        ushort* ou = (ushort*)out;
        if (c < 128) { ou[ob + 128 + c] = f2bf(a); ou[ob + 256 + c] = f2bf(uidf * a); }
        else         { ou[ob + 256 + c] = f2bf(uidf * a); }
      }
    }
  }
}

// ---------------------------------------------------------------------------
extern "C" void kernel_launch(void* const* d_in, const int* in_sizes, int n_in,
                              void* d_out, int out_size, void* d_ws, size_t ws_size,
                              hipStream_t stream) {
  const void* Uq_raw   = d_in[0];
  const void* Uid_raw  = d_in[1];
  const void* mask_raw = d_in[2];
  const void* Wcw_raw  = d_in[3];
  const void* Wcb_raw  = d_in[4];

  char* ws = (char*)d_ws;
  size_t off = 0;
  auto alloc = [&](size_t bytes) -> void* {
    void* p = ws + off; off += (bytes + 255) & ~(size_t)255; return p;
  };
  int*    flag  = (int*)alloc(4);
  ushort* UqB   = (ushort*)alloc((size_t)NB * L * E * 2);  // 4.2 MB
  ushort* UidB  = (ushort*)alloc((size_t)NB * L * E * 2);  // 4.2 MB
  ushort* maskB = (ushort*)alloc((size_t)L * L * 2);       // 8.4 MB
  ushort* WcwB  = (ushort*)alloc(3 * E * 2);
  ushort* WcbB  = (ushort*)alloc(2);
  ushort* Uidw  = (ushort*)alloc((size_t)NB * L * E * 2);  // 4.2 MB
  ushort* T     = (ushort*)alloc((size_t)NB * L * E * 2);  // 4.2 MB
  float*  s_id  = (float*)alloc((size_t)NB * L * 4);
  float*  s_q   = (float*)alloc((size_t)NB * L * 4);

  // adaptive St chunk sizing
  const size_t per_batch = (size_t)L * L * 2;
  size_t avail = (ws_size > off + per_batch) ? (ws_size - off) : per_batch;
  int nb_c = (int)(avail / per_batch);
  if (nb_c < 1) nb_c = 1;
  if (nb_c > NB) nb_c = NB;
  ushort* St = (ushort*)(ws + off);

  const long nU = (long)NB * L * E, nM = (long)L * L;
  k_detect<<<1, 256, 0, stream>>>((const ushort*)Uq_raw, flag);
  k_convert<<<(int)((nU + 255) / 256), 256, 0, stream>>>(Uq_raw, UqB, nU, flag);
  k_convert<<<(int)((nU + 255) / 256), 256, 0, stream>>>(Uid_raw, UidB, nU, flag);
  k_convert<<<(int)((nM + 255) / 256), 256, 0, stream>>>(mask_raw, maskB, nM, flag);
  k_convert<<<2, 256, 0, stream>>>(Wcw_raw, WcwB, 3 * E, flag);
  k_convert<<<1, 256, 0, stream>>>(Wcb_raw, WcbB, 1, flag);

  k_prep<<<NB * L, E, 0, stream>>>(UidB, UqB, WcwB, Uidw, s_id, s_q, d_out, flag);
  for (int b0 = 0; b0 < NB; b0 += nb_c) {
    int nb = (NB - b0 < nb_c) ? (NB - b0) : nb_c;
    k_scores<<<dim3(L / 64, L / 64, nb), 256, 0, stream>>>(UqB, Uidw, s_id, s_q, WcbB, maskB, St, b0);
    k_softmax<<<nb * L, 256, 0, stream>>>(St);
    k_gemm_T<<<dim3(L / 64, E / 64, nb), 256, 0, stream>>>(St, UidB, T, b0);
    k_gemm_A<<<dim3(L / 64, 256 / 64, nb), 256, 0, stream>>>(St, UqB, T, UidB, d_out, b0, flag);
  }
}

// Round 5
// 296.860 us; speedup vs baseline: 1.2836x; 1.2836x over previous
//
#include <hip/hip_runtime.h>

#define L 2048
#define E 128
#define NB 8

typedef float f32x4 __attribute__((ext_vector_type(4)));
typedef short short8 __attribute__((ext_vector_type(8)));
typedef unsigned int u32;

static __device__ inline float bf2f(ushort u) {
  union { float f; u32 i; } v; v.i = ((u32)u) << 16; return v.f;
}
static __device__ inline ushort f2bf(float f) {
  union { float f; u32 i; } v; v.f = f;
  u32 x = v.i;
  return (ushort)((x + 0x7fffu + ((x >> 16) & 1u)) >> 16);  // RTNE
}

// async global->LDS, 16B per lane; lds dest must be wave-uniform base (+lane*16)
__device__ inline void glds16(const ushort* g, ushort* l) {
  __builtin_amdgcn_global_load_lds(
      (const __attribute__((address_space(1))) u32*)(const void*)g,
      (__attribute__((address_space(3))) u32*)(void*)l, 16, 0, 0);
}

// ---------------------------------------------------------------------------
// prep (fused convert): fp32 Uq/Uid -> bf16 UqB/UidB/Uidw; s_id/s_q fp32;
// out[:,:,0:128] = Uid (fp32, bf16-rounded to match ref-from-bf16 inputs)
// ---------------------------------------------------------------------------
__global__ __launch_bounds__(128) void k_prep(const float* __restrict__ Uq,
                                              const float* __restrict__ Uid,
                                              const float* __restrict__ Wcw,
                                              ushort* __restrict__ UqB,
                                              ushort* __restrict__ UidB,
                                              ushort* __restrict__ Uidw,
                                              float* __restrict__ s_id,
                                              float* __restrict__ s_q,
                                              float* __restrict__ out) {
  int r = blockIdx.x;          // 0..B*L-1
  int e = threadIdx.x;         // 0..127
  ushort uqu  = f2bf(Uq[(long)r * E + e]);
  ushort uidu = f2bf(Uid[(long)r * E + e]);
  float uqf = bf2f(uqu), uidf = bf2f(uidu);
  float wid  = bf2f(f2bf(Wcw[e]));
  float wq   = bf2f(f2bf(Wcw[E + e]));
  float wmul = bf2f(f2bf(Wcw[2 * E + e]));
  UqB[(long)r * E + e]  = uqu;
  UidB[(long)r * E + e] = uidu;
  Uidw[(long)r * E + e] = f2bf(uidf * wmul);
  out[(long)r * 512 + e] = uidf;
  float sid = uidf * wid, sq = uqf * wq;
  #pragma unroll
  for (int off = 32; off >= 1; off >>= 1) {
    sid += __shfl_down(sid, off, 64);
    sq  += __shfl_down(sq,  off, 64);
  }
  __shared__ float red[4];
  int wv = threadIdx.x >> 6;
  if ((threadIdx.x & 63) == 0) { red[wv * 2] = sid; red[wv * 2 + 1] = sq; }
  __syncthreads();
  if (threadIdx.x == 0) { s_id[r] = red[0] + red[2]; s_q[r] = red[1] + red[3]; }
}

// ---------------------------------------------------------------------------
// maskT: fp32 mask[i][j] -> bf16 maskT[j][i]
// ---------------------------------------------------------------------------
__global__ __launch_bounds__(256) void k_maskT(const float* __restrict__ mask,
                                               ushort* __restrict__ maskT) {
  __shared__ ushort tile[32][33];
  int j0 = blockIdx.x * 32, i0 = blockIdx.y * 32;
  int tx = threadIdx.x, ty = threadIdx.y;
  #pragma unroll
  for (int r = ty; r < 32; r += 8)
    tile[r][tx] = f2bf(mask[(long)(i0 + r) * L + j0 + tx]);
  __syncthreads();
  #pragma unroll
  for (int r = ty; r < 32; r += 8)
    maskT[(long)(j0 + r) * L + i0 + tx] = tile[tx][r];
}

// ---------------------------------------------------------------------------
// bf16 tile transpose: dst[c*R+r] = src[r*C+c], batched over z (stride R*C)
// ---------------------------------------------------------------------------
__global__ __launch_bounds__(256) void k_tr(const ushort* __restrict__ src,
                                            ushort* __restrict__ dst,
                                            int R, int C) {
  __shared__ ushort tile[32][33];
  long base = (long)blockIdx.z * R * C;
  src += base; dst += base;
  int c0 = blockIdx.x * 32, r0 = blockIdx.y * 32;
  int tx = threadIdx.x, ty = threadIdx.y;
  #pragma unroll
  for (int i = ty; i < 32; i += 8)
    tile[i][tx] = src[(long)(r0 + i) * C + c0 + tx];
  __syncthreads();
  #pragma unroll
  for (int i = ty; i < 32; i += 8)
    dst[(long)(c0 + i) * R + r0 + tx] = tile[tx][i];
}

// ---------------------------------------------------------------------------
// scores (64x64 NT/NT, K=128):
// St[bz,j,i] = (dot(Uq[j],Uidw[i]) + s_q[j] + s_id[i] + bias) * maskT[j,i]
// ---------------------------------------------------------------------------
__global__ __launch_bounds__(256) void k_scores(const ushort* __restrict__ Uq,
                                                const ushort* __restrict__ Uidw,
                                                const float* __restrict__ s_id,
                                                const float* __restrict__ s_q,
                                                float bias_unused,
                                                const float* __restrict__ Wcb,
                                                const ushort* __restrict__ maskT,
                                                ushort* __restrict__ St, int b0) {
  __shared__ ushort ldsA[64 * 40];
  __shared__ ushort ldsB[64 * 40];
  int bz = blockIdx.z, b = b0 + bz;
  int m0 = blockIdx.x * 64;   // j
  int n0 = blockIdx.y * 64;   // i
  const ushort* Ab = Uq   + (long)b * L * E + (long)m0 * E;
  const ushort* Bb = Uidw + (long)b * L * E + (long)n0 * E;
  const int t = threadIdx.x;
  const int lane = t & 63, wv = t >> 6;
  const int srow = t >> 2, skc = (t & 3) << 3;
  const int mrow = lane & 15, quad = lane >> 4;
  f32x4 acc[4] = {};
  for (int k0 = 0; k0 < E; k0 += 32) {
    __syncthreads();
    *(uint4*)&ldsA[srow * 40 + skc] = *(const uint4*)&Ab[(long)srow * E + k0 + skc];
    *(uint4*)&ldsB[srow * 40 + skc] = *(const uint4*)&Bb[(long)srow * E + k0 + skc];
    __syncthreads();
    short8 av = *(const short8*)&ldsA[(wv * 16 + mrow) * 40 + quad * 8];
    #pragma unroll
    for (int nb = 0; nb < 4; nb++) {
      short8 bv = *(const short8*)&ldsB[(nb * 16 + mrow) * 40 + quad * 8];
      acc[nb] = __builtin_amdgcn_mfma_f32_16x16x32_bf16(av, bv, acc[nb], 0, 0, 0);
    }
  }
  float bias = bf2f(f2bf(Wcb[0]));
  int col = lane & 15;
  #pragma unroll
  for (int nb = 0; nb < 4; nb++) {
    int ig = n0 + nb * 16 + col;
    float sidv = s_id[b * L + ig];
    #pragma unroll
    for (int rg = 0; rg < 4; rg++) {
      int jg = m0 + wv * 16 + quad * 4 + rg;
      float v = (acc[nb][rg] + s_q[b * L + jg] + sidv + bias)
                * bf2f(maskT[(long)jg * L + ig]);
      St[(long)bz * L * L + (long)jg * L + ig] = f2bf(v);
    }
  }
}

// ---------------------------------------------------------------------------
// in-place row softmax (length 2048), bf16
// ---------------------------------------------------------------------------
__global__ __launch_bounds__(256) void k_softmax(ushort* __restrict__ S) {
  long r = blockIdx.x;
  ushort* row = S + r * L;
  int t = threadIdx.x;
  uint4 raw = *(const uint4*)&row[t * 8];
  ushort* pr = (ushort*)&raw;
  float v[8];
  float mx = -1e30f;
  #pragma unroll
  for (int q = 0; q < 8; q++) { v[q] = bf2f(pr[q]); mx = fmaxf(mx, v[q]); }
  #pragma unroll
  for (int off = 32; off >= 1; off >>= 1) mx = fmaxf(mx, __shfl_xor(mx, off, 64));
  __shared__ float red[8];
  int wv = t >> 6;
  if ((t & 63) == 0) red[wv] = mx;
  __syncthreads();
  mx = fmaxf(fmaxf(red[0], red[1]), fmaxf(red[2], red[3]));
  float s = 0.f;
  #pragma unroll
  for (int q = 0; q < 8; q++) { v[q] = __expf(v[q] - mx); s += v[q]; }
  #pragma unroll
  for (int off = 32; off >= 1; off >>= 1) s += __shfl_xor(s, off, 64);
  if ((t & 63) == 0) red[4 + wv] = s;
  __syncthreads();
  float inv = 1.0f / (red[4] + red[5] + red[6] + red[7]);
  ushort o[8];
  #pragma unroll
  for (int q = 0; q < 8; q++) o[q] = f2bf(v[q] * inv);
  *(uint4*)&row[t * 8] = *(uint4*)o;
}

// ---------------------------------------------------------------------------
// m97-style 128x128 NT/NT GEMM K-loop: BK=64, global_load_lds width 16.
// A, B row-major with k contiguous; acc[mi][ni] = 16x16 block at
// (mh+mi*16, nh+ni*16), wave quadrant mh=(w&1)*64, nh=(w>>1)*64.
// ---------------------------------------------------------------------------
__device__ inline void gemm128_loop(const ushort* __restrict__ A,
                                    const ushort* __restrict__ B,
                                    long ldA, long ldB, int K,
                                    f32x4 acc[4][4],
                                    ushort* ldsA, ushort* ldsB) {
  const int t = threadIdx.x;
  const int w = t >> 6, lane = t & 63;
  const int mrow = lane & 15, quad = lane >> 4;
  const int lr = lane >> 3;          // staging sub-row 0..7
  const int lc = (lane & 7) * 8;     // staging k-offset
  const int mh = (w & 1) * 64, nh = (w >> 1) * 64;
  for (int k0 = 0; k0 < K; k0 += 64) {
    __syncthreads();                 // previous tile's readers done
    #pragma unroll
    for (int s = 0; s < 4; s++) {
      int row = w * 32 + s * 8 + lr;
      glds16(&A[(long)row * ldA + k0 + lc], &ldsA[w * 2048 + s * 512]);
      glds16(&B[(long)row * ldB + k0 + lc], &ldsB[w * 2048 + s * 512]);
    }
    __syncthreads();                 // vmcnt(0) drained before barrier => filled
    #pragma unroll
    for (int kk = 0; kk < 2; kk++) {
      short8 av[4], bv[4];
      #pragma unroll
      for (int mi = 0; mi < 4; mi++)
        av[mi] = *(const short8*)&ldsA[(mh + mi * 16 + mrow) * 64 + kk * 32 + quad * 8];
      #pragma unroll
      for (int ni = 0; ni < 4; ni++)
        bv[ni] = *(const short8*)&ldsB[(nh + ni * 16 + mrow) * 64 + kk * 32 + quad * 8];
      #pragma unroll
      for (int mi = 0; mi < 4; mi++)
        #pragma unroll
        for (int ni = 0; ni < 4; ni++)
          acc[mi][ni] = __builtin_amdgcn_mfma_f32_16x16x32_bf16(av[mi], bv[ni], acc[mi][ni], 0, 0, 0);
    }
  }
}

// ---------------------------------------------------------------------------
// gemm_T: T[b,j,e] = sum_i Pt[bz,j,i] * UidT[b,e,i]   (NT/NT, 128x128)
// ---------------------------------------------------------------------------
__global__ __launch_bounds__(256) void k_gemm_T(const ushort* __restrict__ Pt,
                                                const ushort* __restrict__ UidT,
                                                ushort* __restrict__ T, int b0) {
  __shared__ ushort ldsA[128 * 64];
  __shared__ ushort ldsB[128 * 64];
  int bz = blockIdx.z, b = b0 + bz;
  int m0 = blockIdx.x * 128;   // j
  int n0 = blockIdx.y * 128;   // e (always 0)
  const ushort* A = Pt   + (long)bz * L * L + (long)m0 * L;
  const ushort* B = UidT + (long)b * E * L + (long)n0 * L;
  f32x4 acc[4][4] = {};
  gemm128_loop(A, B, L, L, L, acc, ldsA, ldsB);
  const int t = threadIdx.x, w = t >> 6, lane = t & 63;
  const int col = lane & 15, quad = lane >> 4;
  const int mh = (w & 1) * 64, nh = (w >> 1) * 64;
  #pragma unroll
  for (int mi = 0; mi < 4; mi++)
    #pragma unroll
    for (int ni = 0; ni < 4; ni++)
      #pragma unroll
      for (int rg = 0; rg < 4; rg++) {
        int jg = m0 + mh + mi * 16 + quad * 4 + rg;
        int eg = n0 + nh + ni * 16 + col;
        T[(long)b * L * E + (long)jg * E + eg] = f2bf(acc[mi][ni][rg]);
      }
}

// ---------------------------------------------------------------------------
// gemm_A: C[b,i,c] = sum_j P[bz,i,j] * X^T[c,j], X^T = UqT (c<128) or Tt
// epilogue -> out cols 128..511 (fp32): A_D2Q, Uid*A_D2Q, Uid*A_Q2D
// ---------------------------------------------------------------------------
__global__ __launch_bounds__(256) void k_gemm_A(const ushort* __restrict__ P,
                                                const ushort* __restrict__ UqT,
                                                const ushort* __restrict__ Tt,
                                                const ushort* __restrict__ UidB,
                                                float* __restrict__ out, int b0) {
  __shared__ ushort ldsA[128 * 64];
  __shared__ ushort ldsB[128 * 64];
  int bz = blockIdx.z, b = b0 + bz;
  int m0 = blockIdx.x * 128;   // i
  int n0 = blockIdx.y * 128;   // c base: 0 -> Uq, 128 -> T
  const ushort* A = P + (long)bz * L * L + (long)m0 * L;
  const ushort* B = (blockIdx.y == 0) ? (UqT + (long)b * E * L)
                                      : (Tt  + (long)b * E * L);
  f32x4 acc[4][4] = {};
  gemm128_loop(A, B, L, L, L, acc, ldsA, ldsB);
  const int t = threadIdx.x, w = t >> 6, lane = t & 63;
  const int col = lane & 15, quad = lane >> 4;
  const int mh = (w & 1) * 64, nh = (w >> 1) * 64;
  #pragma unroll
  for (int mi = 0; mi < 4; mi++)
    #pragma unroll
    for (int ni = 0; ni < 4; ni++)
      #pragma unroll
      for (int rg = 0; rg < 4; rg++) {
        int ig = m0 + mh + mi * 16 + quad * 4 + rg;
        int c  = n0 + nh + ni * 16 + col;
        float a = acc[mi][ni][rg];
        float uidf = bf2f(UidB[(long)b * L * E + (long)ig * E + (c & 127)]);
        long ob = ((long)b * L + ig) * 512;
        if (c < 128) { out[ob + 128 + c] = a; out[ob + 256 + c] = uidf * a; }
        else         { out[ob + 256 + c] = uidf * a; }
      }
}

// ---------------------------------------------------------------------------
extern "C" void kernel_launch(void* const* d_in, const int* in_sizes, int n_in,
                              void* d_out, int out_size, void* d_ws, size_t ws_size,
                              hipStream_t stream) {
  const float* Uq   = (const float*)d_in[0];
  const float* Uid  = (const float*)d_in[1];
  const float* mask = (const float*)d_in[2];
  const float* Wcw  = (const float*)d_in[3];
  const float* Wcb  = (const float*)d_in[4];
  float* out = (float*)d_out;

  char* ws = (char*)d_ws;
  size_t off = 0;
  auto alloc = [&](size_t bytes) -> void* {
    void* p = ws + off; off += (bytes + 255) & ~(size_t)255; return p;
  };
  const size_t nUb = (size_t)NB * L * E * 2;
  ushort* UqB   = (ushort*)alloc(nUb);
  ushort* UidB  = (ushort*)alloc(nUb);
  ushort* Uidw  = (ushort*)alloc(nUb);
  ushort* UqT   = (ushort*)alloc(nUb);
  ushort* UidT  = (ushort*)alloc(nUb);
  ushort* T     = (ushort*)alloc(nUb);
  ushort* Tt    = (ushort*)alloc(nUb);
  ushort* maskT = (ushort*)alloc((size_t)L * L * 2);
  float*  s_id  = (float*)alloc((size_t)NB * L * 4);
  float*  s_q   = (float*)alloc((size_t)NB * L * 4);
  // fixed ~38 MB; chunk St + P each nb_c * 8.4 MB
  const size_t per_batch = (size_t)L * L * 2;
  size_t avail = (ws_size > off + 2 * per_batch) ? (ws_size - off) : 2 * per_batch;
  int nb_c = (int)(avail / (2 * per_batch));
  if (nb_c < 1) nb_c = 1;
  if (nb_c > NB) nb_c = NB;
  ushort* St = (ushort*)(ws + off);                      // becomes Pt in place
  ushort* P  = (ushort*)(ws + off + nb_c * per_batch);

  dim3 tb(32, 8);
  k_prep<<<NB * L, E, 0, stream>>>(Uq, Uid, Wcw, UqB, UidB, Uidw, s_id, s_q, out);
  k_maskT<<<dim3(L / 32, L / 32), tb, 0, stream>>>(mask, maskT);
  k_tr<<<dim3(E / 32, L / 32, NB), tb, 0, stream>>>(UqB, UqT, L, E);
  k_tr<<<dim3(E / 32, L / 32, NB), tb, 0, stream>>>(UidB, UidT, L, E);

  for (int b0 = 0; b0 < NB; b0 += nb_c) {
    int nb = (NB - b0 < nb_c) ? (NB - b0) : nb_c;
    k_scores<<<dim3(L / 64, L / 64, nb), 256, 0, stream>>>(UqB, Uidw, s_id, s_q, 0.f, Wcb, maskT, St, b0);
    k_softmax<<<nb * L, 256, 0, stream>>>(St);                       // -> Pt
    k_tr<<<dim3(L / 32, L / 32, nb), tb, 0, stream>>>(St, P, L, L);  // Pt -> P
    k_gemm_T<<<dim3(L / 128, 1, nb), 256, 0, stream>>>(St, UidT, T, b0);
    k_tr<<<dim3(E / 32, L / 32, nb), tb, 0, stream>>>(T + (long)b0 * L * E,
                                                      Tt + (long)b0 * L * E, L, E);
    k_gemm_A<<<dim3(L / 128, 2, nb), 256, 0, stream>>>(P, UqT, Tt, UidB, out, b0);
  }
}

// Round 6
// 288.359 us; speedup vs baseline: 1.3215x; 1.0295x over previous
//
#include <hip/hip_runtime.h>

#define L 2048
#define E 128
#define NB 8

typedef float f32x4 __attribute__((ext_vector_type(4)));
typedef short short8 __attribute__((ext_vector_type(8)));
typedef unsigned int u32;

static __device__ inline float bf2f(ushort u) {
  union { float f; u32 i; } v; v.i = ((u32)u) << 16; return v.f;
}
static __device__ inline ushort f2bf(float f) {
  union { float f; u32 i; } v; v.f = f;
  u32 x = v.i;
  return (ushort)((x + 0x7fffu + ((x >> 16) & 1u)) >> 16);  // RTNE
}

// async global->LDS, 16B per lane; lds dest is wave-uniform base (+lane*16)
__device__ inline void glds16(const ushort* g, ushort* l) {
  __builtin_amdgcn_global_load_lds(
      (const __attribute__((address_space(1))) u32*)(const void*)g,
      (__attribute__((address_space(3))) u32*)(void*)l, 16, 0, 0);
}

// ---------------------------------------------------------------------------
// prep: fp32 Uq/Uid -> bf16 UqB/UidB/Uidw; s_id/s_q fp32; out[:,:,0:128]=Uid
// ---------------------------------------------------------------------------
__global__ __launch_bounds__(128) void k_prep(const float* __restrict__ Uq,
                                              const float* __restrict__ Uid,
                                              const float* __restrict__ Wcw,
                                              ushort* __restrict__ UqB,
                                              ushort* __restrict__ UidB,
                                              ushort* __restrict__ Uidw,
                                              float* __restrict__ s_id,
                                              float* __restrict__ s_q,
                                              float* __restrict__ out) {
  int r = blockIdx.x;          // 0..B*L-1
  int e = threadIdx.x;         // 0..127
  ushort uqu  = f2bf(Uq[(long)r * E + e]);
  ushort uidu = f2bf(Uid[(long)r * E + e]);
  float uqf = bf2f(uqu), uidf = bf2f(uidu);
  float wid  = bf2f(f2bf(Wcw[e]));
  float wq   = bf2f(f2bf(Wcw[E + e]));
  float wmul = bf2f(f2bf(Wcw[2 * E + e]));
  UqB[(long)r * E + e]  = uqu;
  UidB[(long)r * E + e] = uidu;
  Uidw[(long)r * E + e] = f2bf(uidf * wmul);
  out[(long)r * 512 + e] = uidf;
  float sid = uidf * wid, sq = uqf * wq;
  #pragma unroll
  for (int off = 32; off >= 1; off >>= 1) {
    sid += __shfl_down(sid, off, 64);
    sq  += __shfl_down(sq,  off, 64);
  }
  __shared__ float red[4];
  int wv = threadIdx.x >> 6;
  if ((threadIdx.x & 63) == 0) { red[wv * 2] = sid; red[wv * 2 + 1] = sq; }
  __syncthreads();
  if (threadIdx.x == 0) { s_id[r] = red[0] + red[2]; s_q[r] = red[1] + red[3]; }
}

// ---------------------------------------------------------------------------
// maskT: fp32 mask[i][j] -> bf16 maskT[j][i]
// ---------------------------------------------------------------------------
__global__ __launch_bounds__(256) void k_maskT(const float* __restrict__ mask,
                                               ushort* __restrict__ maskT) {
  __shared__ ushort tile[32][33];
  int j0 = blockIdx.x * 32, i0 = blockIdx.y * 32;
  int tx = threadIdx.x, ty = threadIdx.y;
  #pragma unroll
  for (int r = ty; r < 32; r += 8)
    tile[r][tx] = f2bf(mask[(long)(i0 + r) * L + j0 + tx]);
  __syncthreads();
  #pragma unroll
  for (int r = ty; r < 32; r += 8)
    maskT[(long)(j0 + r) * L + i0 + tx] = tile[tx][r];
}

// ---------------------------------------------------------------------------
// bf16 tile transpose: dst[c*R+r] = src[r*C+c], batched over z (stride R*C)
// ---------------------------------------------------------------------------
__global__ __launch_bounds__(256) void k_tr(const ushort* __restrict__ src,
                                            ushort* __restrict__ dst,
                                            int R, int C) {
  __shared__ ushort tile[32][33];
  long base = (long)blockIdx.z * R * C;
  src += base; dst += base;
  int c0 = blockIdx.x * 32, r0 = blockIdx.y * 32;
  int tx = threadIdx.x, ty = threadIdx.y;
  #pragma unroll
  for (int i = ty; i < 32; i += 8)
    tile[i][tx] = src[(long)(r0 + i) * C + c0 + tx];
  __syncthreads();
  #pragma unroll
  for (int i = ty; i < 32; i += 8)
    dst[(long)(c0 + i) * R + r0 + tx] = tile[tx][i];
}

// ---------------------------------------------------------------------------
// 128x128 NT/NT K-loop: BK=64, glds16. acc[mi][ni] at (mh+mi*16, nh+ni*16),
// mh=(w&1)*64, nh=(w>>1)*64. LDS: 128 rows x 64 ushorts each operand.
// ---------------------------------------------------------------------------
__device__ inline void gemm128_loop(const ushort* __restrict__ A,
                                    const ushort* __restrict__ B,
                                    long ldA, long ldB, int K,
                                    f32x4 acc[4][4],
                                    ushort* ldsA, ushort* ldsB) {
  const int t = threadIdx.x;
  const int w = t >> 6, lane = t & 63;
  const int mrow = lane & 15, quad = lane >> 4;
  const int lr = lane >> 3;          // 0..7
  const int lc = (lane & 7) * 8;     // k-offset
  const int mh = (w & 1) * 64, nh = (w >> 1) * 64;
  for (int k0 = 0; k0 < K; k0 += 64) {
    __syncthreads();
    #pragma unroll
    for (int s = 0; s < 4; s++) {
      int row = w * 32 + s * 8 + lr;
      glds16(&A[(long)row * ldA + k0 + lc], &ldsA[w * 2048 + s * 512]);
      glds16(&B[(long)row * ldB + k0 + lc], &ldsB[w * 2048 + s * 512]);
    }
    __syncthreads();
    #pragma unroll
    for (int kk = 0; kk < 2; kk++) {
      short8 av[4], bv[4];
      #pragma unroll
      for (int mi = 0; mi < 4; mi++)
        av[mi] = *(const short8*)&ldsA[(mh + mi * 16 + mrow) * 64 + kk * 32 + quad * 8];
      #pragma unroll
      for (int ni = 0; ni < 4; ni++)
        bv[ni] = *(const short8*)&ldsB[(nh + ni * 16 + mrow) * 64 + kk * 32 + quad * 8];
      #pragma unroll
      for (int mi = 0; mi < 4; mi++)
        #pragma unroll
        for (int ni = 0; ni < 4; ni++)
          acc[mi][ni] = __builtin_amdgcn_mfma_f32_16x16x32_bf16(av[mi], bv[ni], acc[mi][ni], 0, 0, 0);
    }
  }
}

// ---------------------------------------------------------------------------
// 64x128 (MxN) NT/NT K-loop: BK=64, glds16. 4 waves of 32x64, acc[2][4] at
// (mh+mi*16, nh+ni*16), mh=(w&1)*32, nh=(w>>1)*64. LDS: A 64x64, B 128x64.
// ---------------------------------------------------------------------------
__device__ inline void gemm64x128_loop(const ushort* __restrict__ A,
                                       const ushort* __restrict__ B,
                                       long ldA, long ldB, int K,
                                       f32x4 acc[2][4],
                                       ushort* ldsA, ushort* ldsB) {
  const int t = threadIdx.x;
  const int w = t >> 6, lane = t & 63;
  const int mrow = lane & 15, quad = lane >> 4;
  const int lr = lane >> 3;
  const int lc = (lane & 7) * 8;
  const int mh = (w & 1) * 32, nh = (w >> 1) * 64;
  for (int k0 = 0; k0 < K; k0 += 64) {
    __syncthreads();
    #pragma unroll
    for (int s = 0; s < 2; s++) {
      int row = w * 16 + s * 8 + lr;
      glds16(&A[(long)row * ldA + k0 + lc], &ldsA[w * 1024 + s * 512]);
    }
    #pragma unroll
    for (int s = 0; s < 4; s++) {
      int row = w * 32 + s * 8 + lr;
      glds16(&B[(long)row * ldB + k0 + lc], &ldsB[w * 2048 + s * 512]);
    }
    __syncthreads();
    #pragma unroll
    for (int kk = 0; kk < 2; kk++) {
      short8 av[2], bv[4];
      #pragma unroll
      for (int mi = 0; mi < 2; mi++)
        av[mi] = *(const short8*)&ldsA[(mh + mi * 16 + mrow) * 64 + kk * 32 + quad * 8];
      #pragma unroll
      for (int ni = 0; ni < 4; ni++)
        bv[ni] = *(const short8*)&ldsB[(nh + ni * 16 + mrow) * 64 + kk * 32 + quad * 8];
      #pragma unroll
      for (int mi = 0; mi < 2; mi++)
        #pragma unroll
        for (int ni = 0; ni < 4; ni++)
          acc[mi][ni] = __builtin_amdgcn_mfma_f32_16x16x32_bf16(av[mi], bv[ni], acc[mi][ni], 0, 0, 0);
    }
  }
}

// ---------------------------------------------------------------------------
// scores (128x128, K=128):
// St[bz,j,i] = (dot(Uq[j],Uidw[i]) + s_q[j] + s_id[i] + bias) * maskT[j,i]
// ---------------------------------------------------------------------------
__global__ __launch_bounds__(256) void k_scores(const ushort* __restrict__ Uq,
                                                const ushort* __restrict__ Uidw,
                                                const float* __restrict__ s_id,
                                                const float* __restrict__ s_q,
                                                const float* __restrict__ Wcb,
                                                const ushort* __restrict__ maskT,
                                                ushort* __restrict__ St, int b0) {
  __shared__ ushort ldsA[128 * 64];
  __shared__ ushort ldsB[128 * 64];
  int bz = blockIdx.z, b = b0 + bz;
  int m0 = blockIdx.x * 128;   // j
  int n0 = blockIdx.y * 128;   // i
  const ushort* A = Uq   + (long)b * L * E + (long)m0 * E;
  const ushort* B = Uidw + (long)b * L * E + (long)n0 * E;
  f32x4 acc[4][4] = {};
  gemm128_loop(A, B, E, E, E, acc, ldsA, ldsB);
  float bias = bf2f(f2bf(Wcb[0]));
  const int t = threadIdx.x, w = t >> 6, lane = t & 63;
  const int col = lane & 15, quad = lane >> 4;
  const int mh = (w & 1) * 64, nh = (w >> 1) * 64;
  #pragma unroll
  for (int mi = 0; mi < 4; mi++)
    #pragma unroll
    for (int ni = 0; ni < 4; ni++) {
      int ig = n0 + nh + ni * 16 + col;
      float sidv = s_id[b * L + ig];
      #pragma unroll
      for (int rg = 0; rg < 4; rg++) {
        int jg = m0 + mh + mi * 16 + quad * 4 + rg;
        float v = (acc[mi][ni][rg] + s_q[b * L + jg] + sidv + bias)
                  * bf2f(maskT[(long)jg * L + ig]);
        St[(long)bz * L * L + (long)jg * L + ig] = f2bf(v);
      }
    }
}

// ---------------------------------------------------------------------------
// in-place row softmax (length 2048), bf16
// ---------------------------------------------------------------------------
__global__ __launch_bounds__(256) void k_softmax(ushort* __restrict__ S) {
  long r = blockIdx.x;
  ushort* row = S + r * L;
  int t = threadIdx.x;
  uint4 raw = *(const uint4*)&row[t * 8];
  ushort* pr = (ushort*)&raw;
  float v[8];
  float mx = -1e30f;
  #pragma unroll
  for (int q = 0; q < 8; q++) { v[q] = bf2f(pr[q]); mx = fmaxf(mx, v[q]); }
  #pragma unroll
  for (int off = 32; off >= 1; off >>= 1) mx = fmaxf(mx, __shfl_xor(mx, off, 64));
  __shared__ float red[8];
  int wv = t >> 6;
  if ((t & 63) == 0) red[wv] = mx;
  __syncthreads();
  mx = fmaxf(fmaxf(red[0], red[1]), fmaxf(red[2], red[3]));
  float s = 0.f;
  #pragma unroll
  for (int q = 0; q < 8; q++) { v[q] = __expf(v[q] - mx); s += v[q]; }
  #pragma unroll
  for (int off = 32; off >= 1; off >>= 1) s += __shfl_xor(s, off, 64);
  if ((t & 63) == 0) red[4 + wv] = s;
  __syncthreads();
  float inv = 1.0f / (red[4] + red[5] + red[6] + red[7]);
  ushort o[8];
  #pragma unroll
  for (int q = 0; q < 8; q++) o[q] = f2bf(v[q] * inv);
  *(uint4*)&row[t * 8] = *(uint4*)o;
}

// ---------------------------------------------------------------------------
// gemm_T (64x128): T[b,j,e] = sum_i Pt[bz,j,i] * UidT[b,e,i]
// ---------------------------------------------------------------------------
__global__ __launch_bounds__(256) void k_gemm_T(const ushort* __restrict__ Pt,
                                                const ushort* __restrict__ UidT,
                                                ushort* __restrict__ T, int b0) {
  __shared__ ushort ldsA[64 * 64];    // 8 KB
  __shared__ ushort ldsB[128 * 64];   // 16 KB
  int bz = blockIdx.z, b = b0 + bz;
  int m0 = blockIdx.x * 64;   // j
  const ushort* A = Pt   + (long)bz * L * L + (long)m0 * L;
  const ushort* B = UidT + (long)b * E * L;
  f32x4 acc[2][4] = {};
  gemm64x128_loop(A, B, L, L, L, acc, ldsA, ldsB);
  const int t = threadIdx.x, w = t >> 6, lane = t & 63;
  const int col = lane & 15, quad = lane >> 4;
  const int mh = (w & 1) * 32, nh = (w >> 1) * 64;
  #pragma unroll
  for (int mi = 0; mi < 2; mi++)
    #pragma unroll
    for (int ni = 0; ni < 4; ni++)
      #pragma unroll
      for (int rg = 0; rg < 4; rg++) {
        int jg = m0 + mh + mi * 16 + quad * 4 + rg;
        int eg = nh + ni * 16 + col;
        T[(long)b * L * E + (long)jg * E + eg] = f2bf(acc[mi][ni][rg]);
      }
}

// ---------------------------------------------------------------------------
// gemm_A (64x128): C[b,i,c] = sum_j P[bz,i,j] * X^T[c,j], X^T = UqT | Tt
// epilogue -> out cols 128..511 (fp32): A_D2Q, Uid*A_D2Q, Uid*A_Q2D
// ---------------------------------------------------------------------------
__global__ __launch_bounds__(256) void k_gemm_A(const ushort* __restrict__ P,
                                                const ushort* __restrict__ UqT,
                                                const ushort* __restrict__ Tt,
                                                const ushort* __restrict__ UidB,
                                                float* __restrict__ out, int b0) {
  __shared__ ushort ldsA[64 * 64];
  __shared__ ushort ldsB[128 * 64];
  int bz = blockIdx.z, b = b0 + bz;
  int m0 = blockIdx.x * 64;    // i
  int n0 = blockIdx.y * 128;   // c base: 0 -> Uq, 128 -> T
  const ushort* A = P + (long)bz * L * L + (long)m0 * L;
  const ushort* B = (blockIdx.y == 0) ? (UqT + (long)b * E * L)
                                      : (Tt  + (long)b * E * L);
  f32x4 acc[2][4] = {};
  gemm64x128_loop(A, B, L, L, L, acc, ldsA, ldsB);
  const int t = threadIdx.x, w = t >> 6, lane = t & 63;
  const int col = lane & 15, quad = lane >> 4;
  const int mh = (w & 1) * 32, nh = (w >> 1) * 64;
  #pragma unroll
  for (int mi = 0; mi < 2; mi++)
    #pragma unroll
    for (int ni = 0; ni < 4; ni++)
      #pragma unroll
      for (int rg = 0; rg < 4; rg++) {
        int ig = m0 + mh + mi * 16 + quad * 4 + rg;
        int c  = n0 + nh + ni * 16 + col;
        float a = acc[mi][ni][rg];
        float uidf = bf2f(UidB[(long)b * L * E + (long)ig * E + (c & 127)]);
        long ob = ((long)b * L + ig) * 512;
        if (c < 128) { out[ob + 128 + c] = a; out[ob + 256 + c] = uidf * a; }
        else         { out[ob + 256 + c] = uidf * a; }
      }
}

// ---------------------------------------------------------------------------
extern "C" void kernel_launch(void* const* d_in, const int* in_sizes, int n_in,
                              void* d_out, int out_size, void* d_ws, size_t ws_size,
                              hipStream_t stream) {
  const float* Uq   = (const float*)d_in[0];
  const float* Uid  = (const float*)d_in[1];
  const float* mask = (const float*)d_in[2];
  const float* Wcw  = (const float*)d_in[3];
  const float* Wcb  = (const float*)d_in[4];
  float* out = (float*)d_out;

  char* ws = (char*)d_ws;
  size_t off = 0;
  auto alloc = [&](size_t bytes) -> void* {
    void* p = ws + off; off += (bytes + 255) & ~(size_t)255; return p;
  };
  const size_t nUb = (size_t)NB * L * E * 2;
  ushort* UqB   = (ushort*)alloc(nUb);
  ushort* UidB  = (ushort*)alloc(nUb);
  ushort* Uidw  = (ushort*)alloc(nUb);
  ushort* UqT   = (ushort*)alloc(nUb);
  ushort* UidT  = (ushort*)alloc(nUb);
  ushort* T     = (ushort*)alloc(nUb);
  ushort* Tt    = (ushort*)alloc(nUb);
  ushort* maskT = (ushort*)alloc((size_t)L * L * 2);
  float*  s_id  = (float*)alloc((size_t)NB * L * 4);
  float*  s_q   = (float*)alloc((size_t)NB * L * 4);
  // fixed ~38 MB; chunk: St + P each nb_c * 8.4 MB
  const size_t per_batch = (size_t)L * L * 2;
  size_t avail = (ws_size > off + 2 * per_batch) ? (ws_size - off) : 2 * per_batch;
  int nb_c = (int)(avail / (2 * per_batch));
  if (nb_c < 1) nb_c = 1;
  if (nb_c > NB) nb_c = NB;
  ushort* St = (ushort*)(ws + off);                      // becomes Pt in place
  ushort* P  = (ushort*)(ws + off + nb_c * per_batch);

  dim3 tb(32, 8);
  k_prep<<<NB * L, E, 0, stream>>>(Uq, Uid, Wcw, UqB, UidB, Uidw, s_id, s_q, out);
  k_maskT<<<dim3(L / 32, L / 32), tb, 0, stream>>>(mask, maskT);
  k_tr<<<dim3(E / 32, L / 32, NB), tb, 0, stream>>>(UqB, UqT, L, E);
  k_tr<<<dim3(E / 32, L / 32, NB), tb, 0, stream>>>(UidB, UidT, L, E);

  for (int b0 = 0; b0 < NB; b0 += nb_c) {
    int nb = (NB - b0 < nb_c) ? (NB - b0) : nb_c;
    k_scores<<<dim3(L / 128, L / 128, nb), 256, 0, stream>>>(UqB, Uidw, s_id, s_q, Wcb, maskT, St, b0);
    k_softmax<<<nb * L, 256, 0, stream>>>(St);                       // -> Pt
    k_tr<<<dim3(L / 32, L / 32, nb), tb, 0, stream>>>(St, P, L, L);  // Pt -> P
    k_gemm_T<<<dim3(L / 64, 1, nb), 256, 0, stream>>>(St, UidT, T, b0);
    k_tr<<<dim3(E / 32, L / 32, nb), tb, 0, stream>>>(T + (long)b0 * L * E,
                                                      Tt + (long)b0 * L * E, L, E);
    k_gemm_A<<<dim3(L / 64, 2, nb), 256, 0, stream>>>(P, UqT, Tt, UidB, out, b0);
  }
}

// Round 7
// 281.366 us; speedup vs baseline: 1.3543x; 1.0249x over previous
//
#include <hip/hip_runtime.h>

#define L 2048
#define E 128
#define NB 8

typedef float f32x4 __attribute__((ext_vector_type(4)));
typedef short short8 __attribute__((ext_vector_type(8)));
typedef unsigned int u32;

static __device__ inline float bf2f(ushort u) {
  union { float f; u32 i; } v; v.i = ((u32)u) << 16; return v.f;
}
static __device__ inline ushort f2bf(float f) {
  union { float f; u32 i; } v; v.f = f;
  u32 x = v.i;
  return (ushort)((x + 0x7fffu + ((x >> 16) & 1u)) >> 16);  // RTNE
}

// async global->LDS, 16B per lane; lds dest is wave-uniform base (+lane*16)
__device__ inline void glds16(const ushort* g, ushort* l) {
  __builtin_amdgcn_global_load_lds(
      (const __attribute__((address_space(1))) u32*)(const void*)g,
      (__attribute__((address_space(3))) u32*)(void*)l, 16, 0, 0);
}

// ---------------------------------------------------------------------------
// prep: fp32 Uq/Uid -> bf16 UqB/UidB/Uidw; s_id/s_q fp32; out[:,:,0:128]=Uid
// ---------------------------------------------------------------------------
__global__ __launch_bounds__(128) void k_prep(const float* __restrict__ Uq,
                                              const float* __restrict__ Uid,
                                              const float* __restrict__ Wcw,
                                              ushort* __restrict__ UqB,
                                              ushort* __restrict__ UidB,
                                              ushort* __restrict__ Uidw,
                                              float* __restrict__ s_id,
                                              float* __restrict__ s_q,
                                              float* __restrict__ out) {
  int r = blockIdx.x;          // 0..B*L-1
  int e = threadIdx.x;         // 0..127
  ushort uqu  = f2bf(Uq[(long)r * E + e]);
  ushort uidu = f2bf(Uid[(long)r * E + e]);
  float uqf = bf2f(uqu), uidf = bf2f(uidu);
  float wid  = bf2f(f2bf(Wcw[e]));
  float wq   = bf2f(f2bf(Wcw[E + e]));
  float wmul = bf2f(f2bf(Wcw[2 * E + e]));
  UqB[(long)r * E + e]  = uqu;
  UidB[(long)r * E + e] = uidu;
  Uidw[(long)r * E + e] = f2bf(uidf * wmul);
  out[(long)r * 512 + e] = uidf;
  float sid = uidf * wid, sq = uqf * wq;
  #pragma unroll
  for (int off = 32; off >= 1; off >>= 1) {
    sid += __shfl_down(sid, off, 64);
    sq  += __shfl_down(sq,  off, 64);
  }
  __shared__ float red[4];
  int wv = threadIdx.x >> 6;
  if ((threadIdx.x & 63) == 0) { red[wv * 2] = sid; red[wv * 2 + 1] = sq; }
  __syncthreads();
  if (threadIdx.x == 0) { s_id[r] = red[0] + red[2]; s_q[r] = red[1] + red[3]; }
}

// ---------------------------------------------------------------------------
// maskT: fp32 mask[i][j] -> bf16 maskT[j][i]
// ---------------------------------------------------------------------------
__global__ __launch_bounds__(256) void k_maskT(const float* __restrict__ mask,
                                               ushort* __restrict__ maskT) {
  __shared__ ushort tile[32][33];
  int j0 = blockIdx.x * 32, i0 = blockIdx.y * 32;
  int tx = threadIdx.x, ty = threadIdx.y;
  #pragma unroll
  for (int r = ty; r < 32; r += 8)
    tile[r][tx] = f2bf(mask[(long)(i0 + r) * L + j0 + tx]);
  __syncthreads();
  #pragma unroll
  for (int r = ty; r < 32; r += 8)
    maskT[(long)(j0 + r) * L + i0 + tx] = tile[tx][r];
}

// ---------------------------------------------------------------------------
// bf16 tile transpose: dst[c*R+r] = src[r*C+c], batched over z (stride R*C)
// ---------------------------------------------------------------------------
__global__ __launch_bounds__(256) void k_tr(const ushort* __restrict__ src,
                                            ushort* __restrict__ dst,
                                            int R, int C) {
  __shared__ ushort tile[32][33];
  long base = (long)blockIdx.z * R * C;
  src += base; dst += base;
  int c0 = blockIdx.x * 32, r0 = blockIdx.y * 32;
  int tx = threadIdx.x, ty = threadIdx.y;
  #pragma unroll
  for (int i = ty; i < 32; i += 8)
    tile[i][tx] = src[(long)(r0 + i) * C + c0 + tx];
  __syncthreads();
  #pragma unroll
  for (int i = ty; i < 32; i += 8)
    dst[(long)(c0 + i) * R + r0 + tx] = tile[tx][i];
}

// ---------------------------------------------------------------------------
// 128x128 NT/NT K-loop: BK=64, glds16. acc[mi][ni] at (mh+mi*16, nh+ni*16),
// mh=(w&1)*64, nh=(w>>1)*64. LDS: 128 rows x 64 ushorts each operand.
// ---------------------------------------------------------------------------
__device__ inline void gemm128_loop(const ushort* __restrict__ A,
                                    const ushort* __restrict__ B,
                                    long ldA, long ldB, int K,
                                    f32x4 acc[4][4],
                                    ushort* ldsA, ushort* ldsB) {
  const int t = threadIdx.x;
  const int w = t >> 6, lane = t & 63;
  const int mrow = lane & 15, quad = lane >> 4;
  const int lr = lane >> 3;          // 0..7
  const int lc = (lane & 7) * 8;     // k-offset
  const int mh = (w & 1) * 64, nh = (w >> 1) * 64;
  for (int k0 = 0; k0 < K; k0 += 64) {
    __syncthreads();
    #pragma unroll
    for (int s = 0; s < 4; s++) {
      int row = w * 32 + s * 8 + lr;
      glds16(&A[(long)row * ldA + k0 + lc], &ldsA[w * 2048 + s * 512]);
      glds16(&B[(long)row * ldB + k0 + lc], &ldsB[w * 2048 + s * 512]);
    }
    __syncthreads();
    #pragma unroll
    for (int kk = 0; kk < 2; kk++) {
      short8 av[4], bv[4];
      #pragma unroll
      for (int mi = 0; mi < 4; mi++)
        av[mi] = *(const short8*)&ldsA[(mh + mi * 16 + mrow) * 64 + kk * 32 + quad * 8];
      #pragma unroll
      for (int ni = 0; ni < 4; ni++)
        bv[ni] = *(const short8*)&ldsB[(nh + ni * 16 + mrow) * 64 + kk * 32 + quad * 8];
      #pragma unroll
      for (int mi = 0; mi < 4; mi++)
        #pragma unroll
        for (int ni = 0; ni < 4; ni++)
          acc[mi][ni] = __builtin_amdgcn_mfma_f32_16x16x32_bf16(av[mi], bv[ni], acc[mi][ni], 0, 0, 0);
    }
  }
}

// ---------------------------------------------------------------------------
// 64x128 (MxN) NT/NT K-loop: BK=64, glds16. acc[2][4] at (mh+mi*16,nh+ni*16),
// mh=(w&1)*32, nh=(w>>1)*64. LDS: A 64x64, B 128x64.
// ---------------------------------------------------------------------------
__device__ inline void gemm64x128_loop(const ushort* __restrict__ A,
                                       const ushort* __restrict__ B,
                                       long ldA, long ldB, int K,
                                       f32x4 acc[2][4],
                                       ushort* ldsA, ushort* ldsB) {
  const int t = threadIdx.x;
  const int w = t >> 6, lane = t & 63;
  const int mrow = lane & 15, quad = lane >> 4;
  const int lr = lane >> 3;
  const int lc = (lane & 7) * 8;
  const int mh = (w & 1) * 32, nh = (w >> 1) * 64;
  for (int k0 = 0; k0 < K; k0 += 64) {
    __syncthreads();
    #pragma unroll
    for (int s = 0; s < 2; s++) {
      int row = w * 16 + s * 8 + lr;
      glds16(&A[(long)row * ldA + k0 + lc], &ldsA[w * 1024 + s * 512]);
    }
    #pragma unroll
    for (int s = 0; s < 4; s++) {
      int row = w * 32 + s * 8 + lr;
      glds16(&B[(long)row * ldB + k0 + lc], &ldsB[w * 2048 + s * 512]);
    }
    __syncthreads();
    #pragma unroll
    for (int kk = 0; kk < 2; kk++) {
      short8 av[2], bv[4];
      #pragma unroll
      for (int mi = 0; mi < 2; mi++)
        av[mi] = *(const short8*)&ldsA[(mh + mi * 16 + mrow) * 64 + kk * 32 + quad * 8];
      #pragma unroll
      for (int ni = 0; ni < 4; ni++)
        bv[ni] = *(const short8*)&ldsB[(nh + ni * 16 + mrow) * 64 + kk * 32 + quad * 8];
      #pragma unroll
      for (int mi = 0; mi < 2; mi++)
        #pragma unroll
        for (int ni = 0; ni < 4; ni++)
          acc[mi][ni] = __builtin_amdgcn_mfma_f32_16x16x32_bf16(av[mi], bv[ni], acc[mi][ni], 0, 0, 0);
    }
  }
}

// ---------------------------------------------------------------------------
// scores (128x128, K=128) with LDS-repacked coalesced epilogue:
// St[bz,j,i] = (dot(Uq[j],Uidw[i]) + s_q[j] + s_id[i] + bias) * maskT[j,i]
// ---------------------------------------------------------------------------
#define CST 136   // C-tile LDS stride (272 B rows: 16B-aligned; quads 2-way free)
__global__ __launch_bounds__(256) void k_scores(const ushort* __restrict__ Uq,
                                                const ushort* __restrict__ Uidw,
                                                const float* __restrict__ s_id,
                                                const float* __restrict__ s_q,
                                                const float* __restrict__ Wcb,
                                                const ushort* __restrict__ maskT,
                                                ushort* __restrict__ St, int b0) {
  __shared__ ushort smem[128 * CST];     // 34816 B; staging aliases front 32 KB
  ushort* ldsA = smem;
  ushort* ldsB = smem + 8192;
  int bz = blockIdx.z, b = b0 + bz;
  int m0 = blockIdx.x * 128;   // j
  int n0 = blockIdx.y * 128;   // i
  const ushort* A = Uq   + (long)b * L * E + (long)m0 * E;
  const ushort* B = Uidw + (long)b * L * E + (long)n0 * E;
  f32x4 acc[4][4] = {};
  gemm128_loop(A, B, E, E, E, acc, ldsA, ldsB);
  float bias = bf2f(f2bf(Wcb[0]));
  const int t = threadIdx.x, w = t >> 6, lane = t & 63;
  const int col = lane & 15, quad = lane >> 4;
  const int mh = (w & 1) * 64, nh = (w >> 1) * 64;
  __syncthreads();   // staging reads done before C-tile overwrites smem
  #pragma unroll
  for (int ni = 0; ni < 4; ni++) {
    int ig = n0 + nh + ni * 16 + col;
    float sidv = s_id[b * L + ig];
    #pragma unroll
    for (int mi = 0; mi < 4; mi++)
      #pragma unroll
      for (int rg = 0; rg < 4; rg++) {
        int jl = mh + mi * 16 + quad * 4 + rg;
        float v = acc[mi][ni][rg] + s_q[b * L + m0 + jl] + sidv + bias;
        smem[jl * CST + nh + ni * 16 + col] = f2bf(v);
      }
  }
  __syncthreads();
  // coalesced mask-multiply + store: thread -> (row j = t>>1, 64-col segment)
  int j = t >> 1, seg = (t & 1) * 64;
  ushort* Sp = St + (long)bz * L * L + (long)(m0 + j) * L + n0 + seg;
  const ushort* Mp = maskT + (long)(m0 + j) * L + n0 + seg;
  #pragma unroll
  for (int cc = 0; cc < 64; cc += 8) {
    uint4 mv = *(const uint4*)&Mp[cc];
    uint4 cv = *(const uint4*)&smem[j * CST + seg + cc];
    ushort* mp = (ushort*)&mv;
    ushort* cp = (ushort*)&cv;
    ushort o[8];
    #pragma unroll
    for (int k = 0; k < 8; k++) o[k] = f2bf(bf2f(cp[k]) * bf2f(mp[k]));
    *(uint4*)&Sp[cc] = *(uint4*)o;
  }
}

// ---------------------------------------------------------------------------
// fused softmax + transpose: St rows (j, len 2048) -> Pt (in-place) and
// P[i*L+j]. Block = 32 j-rows of one batch. Grid (L/32, nb).
// ---------------------------------------------------------------------------
__global__ __launch_bounds__(256) void k_softmax_tr(ushort* __restrict__ St,
                                                    ushort* __restrict__ P) {
  int bz = blockIdx.y;
  int j0 = blockIdx.x * 32;
  ushort* Sb = St + (long)bz * L * L;
  ushort* Pb = P  + (long)bz * L * L;
  int t = threadIdx.x, w = t >> 6, lane = t & 63;
  __shared__ float mrow[32], lrow[32];
  __shared__ ushort tile[128 * 33];
  // phase 1: per-row max & sumexp (wave per row, 8 rows/wave)
  for (int rr = w; rr < 32; rr += 4) {
    const ushort* row = Sb + (long)(j0 + rr) * L;
    uint4 q[4];
    #pragma unroll
    for (int c = 0; c < 4; c++) q[c] = *(const uint4*)&row[lane * 8 + c * 512];
    float v[32]; float mx = -1e30f;
    #pragma unroll
    for (int c = 0; c < 4; c++) {
      ushort* pr = (ushort*)&q[c];
      #pragma unroll
      for (int k = 0; k < 8; k++) { v[c * 8 + k] = bf2f(pr[k]); mx = fmaxf(mx, v[c * 8 + k]); }
    }
    #pragma unroll
    for (int off = 32; off >= 1; off >>= 1) mx = fmaxf(mx, __shfl_xor(mx, off, 64));
    float s = 0.f;
    #pragma unroll
    for (int k = 0; k < 32; k++) s += __expf(v[k] - mx);
    #pragma unroll
    for (int off = 32; off >= 1; off >>= 1) s += __shfl_xor(s, off, 64);
    if (lane == 0) { mrow[rr] = mx; lrow[rr] = 1.0f / s; }
  }
  __syncthreads();
  // phase 2: normalize, write Pt in place + P transposed via LDS tile
  int r = t >> 3, c0 = (t & 7) * 16;   // row 0..31, 16-elem segment of 128-chunk
  float m = mrow[r], inv = lrow[r];
  int il = t >> 1, half = (t & 1) * 16;
  for (int i0 = 0; i0 < L; i0 += 128) {
    ushort* src = Sb + (long)(j0 + r) * L + i0 + c0;
    uint4 q0 = *(const uint4*)src;
    uint4 q1 = *(const uint4*)(src + 8);
    ushort o[16];
    ushort* pr = (ushort*)&q0;
    #pragma unroll
    for (int k = 0; k < 8; k++) o[k] = f2bf(__expf(bf2f(pr[k]) - m) * inv);
    pr = (ushort*)&q1;
    #pragma unroll
    for (int k = 0; k < 8; k++) o[8 + k] = f2bf(__expf(bf2f(pr[k]) - m) * inv);
    *(uint4*)src = *(uint4*)&o[0];
    *(uint4*)(src + 8) = *(uint4*)&o[8];
    __syncthreads();   // previous iteration's tile readers done
    #pragma unroll
    for (int k = 0; k < 16; k++) tile[(c0 + k) * 33 + r] = o[k];
    __syncthreads();
    ushort po[16];
    #pragma unroll
    for (int jj = 0; jj < 16; jj++) po[jj] = tile[il * 33 + half + jj];
    ushort* pd = Pb + (long)(i0 + il) * L + j0 + half;
    *(uint4*)pd = *(uint4*)&po[0];
    *(uint4*)(pd + 8) = *(uint4*)&po[8];
  }
}

// ---------------------------------------------------------------------------
// gemm_T (64x128): T[b,j,e] = sum_i Pt[bz,j,i] * UidT[b,e,i]
// ---------------------------------------------------------------------------
__global__ __launch_bounds__(256) void k_gemm_T(const ushort* __restrict__ Pt,
                                                const ushort* __restrict__ UidT,
                                                ushort* __restrict__ T, int b0) {
  __shared__ ushort ldsA[64 * 64];    // 8 KB
  __shared__ ushort ldsB[128 * 64];   // 16 KB
  int bz = blockIdx.z, b = b0 + bz;
  int m0 = blockIdx.x * 64;   // j
  const ushort* A = Pt   + (long)bz * L * L + (long)m0 * L;
  const ushort* B = UidT + (long)b * E * L;
  f32x4 acc[2][4] = {};
  gemm64x128_loop(A, B, L, L, L, acc, ldsA, ldsB);
  const int t = threadIdx.x, w = t >> 6, lane = t & 63;
  const int col = lane & 15, quad = lane >> 4;
  const int mh = (w & 1) * 32, nh = (w >> 1) * 64;
  #pragma unroll
  for (int mi = 0; mi < 2; mi++)
    #pragma unroll
    for (int ni = 0; ni < 4; ni++)
      #pragma unroll
      for (int rg = 0; rg < 4; rg++) {
        int jg = m0 + mh + mi * 16 + quad * 4 + rg;
        int eg = nh + ni * 16 + col;
        T[(long)b * L * E + (long)jg * E + eg] = f2bf(acc[mi][ni][rg]);
      }
}

// ---------------------------------------------------------------------------
// gemm_A (64x128): C[b,i,c] = sum_j P[bz,i,j] * X^T[c,j], X^T = UqT | Tt
// epilogue -> out cols 128..511 (fp32): A_D2Q, Uid*A_D2Q, Uid*A_Q2D
// ---------------------------------------------------------------------------
__global__ __launch_bounds__(256) void k_gemm_A(const ushort* __restrict__ P,
                                                const ushort* __restrict__ UqT,
                                                const ushort* __restrict__ Tt,
                                                const ushort* __restrict__ UidB,
                                                float* __restrict__ out, int b0) {
  __shared__ ushort ldsA[64 * 64];
  __shared__ ushort ldsB[128 * 64];
  int bz = blockIdx.z, b = b0 + bz;
  int m0 = blockIdx.x * 64;    // i
  int n0 = blockIdx.y * 128;   // c base: 0 -> Uq, 128 -> T
  const ushort* A = P + (long)bz * L * L + (long)m0 * L;
  const ushort* B = (blockIdx.y == 0) ? (UqT + (long)b * E * L)
                                      : (Tt  + (long)b * E * L);
  f32x4 acc[2][4] = {};
  gemm64x128_loop(A, B, L, L, L, acc, ldsA, ldsB);
  const int t = threadIdx.x, w = t >> 6, lane = t & 63;
  const int col = lane & 15, quad = lane >> 4;
  const int mh = (w & 1) * 32, nh = (w >> 1) * 64;
  #pragma unroll
  for (int mi = 0; mi < 2; mi++)
    #pragma unroll
    for (int ni = 0; ni < 4; ni++)
      #pragma unroll
      for (int rg = 0; rg < 4; rg++) {
        int ig = m0 + mh + mi * 16 + quad * 4 + rg;
        int c  = n0 + nh + ni * 16 + col;
        float a = acc[mi][ni][rg];
        float uidf = bf2f(UidB[(long)b * L * E + (long)ig * E + (c & 127)]);
        long ob = ((long)b * L + ig) * 512;
        if (c < 128) { out[ob + 128 + c] = a; out[ob + 256 + c] = uidf * a; }
        else         { out[ob + 256 + c] = uidf * a; }
      }
}

// ---------------------------------------------------------------------------
extern "C" void kernel_launch(void* const* d_in, const int* in_sizes, int n_in,
                              void* d_out, int out_size, void* d_ws, size_t ws_size,
                              hipStream_t stream) {
  const float* Uq   = (const float*)d_in[0];
  const float* Uid  = (const float*)d_in[1];
  const float* mask = (const float*)d_in[2];
  const float* Wcw  = (const float*)d_in[3];
  const float* Wcb  = (const float*)d_in[4];
  float* out = (float*)d_out;

  char* ws = (char*)d_ws;
  size_t off = 0;
  auto alloc = [&](size_t bytes) -> void* {
    void* p = ws + off; off += (bytes + 255) & ~(size_t)255; return p;
  };
  const size_t nUb = (size_t)NB * L * E * 2;
  ushort* UqB   = (ushort*)alloc(nUb);
  ushort* UidB  = (ushort*)alloc(nUb);
  ushort* Uidw  = (ushort*)alloc(nUb);
  ushort* UqT   = (ushort*)alloc(nUb);
  ushort* UidT  = (ushort*)alloc(nUb);
  ushort* T     = (ushort*)alloc(nUb);
  ushort* Tt    = (ushort*)alloc(nUb);
  ushort* maskT = (ushort*)alloc((size_t)L * L * 2);
  float*  s_id  = (float*)alloc((size_t)NB * L * 4);
  float*  s_q   = (float*)alloc((size_t)NB * L * 4);
  // fixed ~38 MB; chunk: St + P each nb_c * 8.4 MB
  const size_t per_batch = (size_t)L * L * 2;
  size_t avail = (ws_size > off + 2 * per_batch) ? (ws_size - off) : 2 * per_batch;
  int nb_c = (int)(avail / (2 * per_batch));
  if (nb_c < 1) nb_c = 1;
  if (nb_c > NB) nb_c = NB;
  ushort* St = (ushort*)(ws + off);                      // becomes Pt in place
  ushort* P  = (ushort*)(ws + off + nb_c * per_batch);

  dim3 tb(32, 8);
  k_prep<<<NB * L, E, 0, stream>>>(Uq, Uid, Wcw, UqB, UidB, Uidw, s_id, s_q, out);
  k_maskT<<<dim3(L / 32, L / 32), tb, 0, stream>>>(mask, maskT);
  k_tr<<<dim3(E / 32, L / 32, NB), tb, 0, stream>>>(UqB, UqT, L, E);
  k_tr<<<dim3(E / 32, L / 32, NB), tb, 0, stream>>>(UidB, UidT, L, E);

  for (int b0 = 0; b0 < NB; b0 += nb_c) {
    int nb = (NB - b0 < nb_c) ? (NB - b0) : nb_c;
    k_scores<<<dim3(L / 128, L / 128, nb), 256, 0, stream>>>(UqB, Uidw, s_id, s_q, Wcb, maskT, St, b0);
    k_softmax_tr<<<dim3(L / 32, nb), 256, 0, stream>>>(St, P);       // St->Pt, +P
    k_gemm_T<<<dim3(L / 64, 1, nb), 256, 0, stream>>>(St, UidT, T, b0);
    k_tr<<<dim3(E / 32, L / 32, nb), tb, 0, stream>>>(T + (long)b0 * L * E,
                                                      Tt + (long)b0 * L * E, L, E);
    k_gemm_A<<<dim3(L / 64, 2, nb), 256, 0, stream>>>(P, UqT, Tt, UidB, out, b0);
  }
}